// Round 12
// baseline (143.431 us; speedup 1.0000x reference)
//
#include <hip/hip_runtime.h>
#include <hip/hip_cooperative_groups.h>

namespace cg = cooperative_groups;

// Forward collapse:
//   c = y[b]; k = argmax_k(logits[c,k] + gumbel[c,b,k]) (first max)
//   x[b,:] = L[c,k] @ z[b,:] + m[c,k,:]
//
// Round 12: ONE cooperative kernel. Grid (100 ck, 4 jq) = 400 blocks, 256 thr,
// 33 KB LDS (4 blocks/CU capacity -> all co-resident; grid.sync legal).
//   phase 1: all blocks stage+convert their L-quarter (bf16);
//            blocks 0..31 ALSO do fp32-exact selection for their 256 samples
//            -> ck_arr (overlaps with other blocks' staging).
//   grid.sync()
//   phase 2: scan ck_arr (8 KB, L2-broadcast) -> LDS list; stage z rows bf16;
//            R11-verified mfma_f32_16x16x32_bf16 core; fp32 epilogue.

#define N_Z 128
#define N_COMP 10
#define N_CLASSES 10
#define N_CK (N_CLASSES * N_COMP)
#define ZCAP 96          // z rows per chunk (chunk loop covers n > 96)
#define LIST_CAP 256

typedef __attribute__((ext_vector_type(4))) __bf16 bf16x4;
typedef __attribute__((ext_vector_type(8))) __bf16 bf16x8;
typedef __attribute__((ext_vector_type(4))) float f32x4;

__global__ __launch_bounds__(256) void k_coop(
    const float* __restrict__ z, const int* __restrict__ y,
    const float* __restrict__ gumbel, const float* __restrict__ m,
    const float* __restrict__ L, const float* __restrict__ logits,
    float* __restrict__ out, unsigned char* __restrict__ ck_arr, int bs)
{
    const int ck  = blockIdx.x;
    const int jq  = blockIdx.y;                         // j range [jq*32, jq*32+32)
    const int t   = threadIdx.x;
    const int bid = blockIdx.y * gridDim.x + blockIdx.x; // 0..399

    __shared__ __align__(16) __bf16 Lsb[32 * 128];   // 8 KB, row-major [jl][i]
    __shared__ __align__(16) __bf16 zsb[ZCAP * 128]; // 24 KB, row-major [sl][i]
    __shared__ int list[LIST_CAP];                   // 1 KB
    __shared__ int cnt;

    if (t == 0) cnt = 0;

    // ---- phase 1a: stage + convert L quarter (32x128 fp32 = 1024 f4, 4/thr) ----
    {
        const float4* Lg4 = (const float4*)(L + ((size_t)ck * N_Z + jq * 32) * N_Z);
        #pragma unroll
        for (int p = 0; p < 4; ++p) {
            int f = p * 256 + t;              // float4 index; row = f>>5, col4 = f&31
            float4 v = Lg4[f];
            bf16x4 b4 = { (__bf16)v.x, (__bf16)v.y, (__bf16)v.z, (__bf16)v.w };
            *(bf16x4*)&Lsb[f * 4] = b4;       // 8-B store, row-major
        }
    }

    // ---- phase 1b: blocks 0..31 do fp32-exact selection (256 samples each) ----
    const int nselblk = bs >> 8;              // 32 for bs=8192
    if (bid < nselblk) {
        int b = bid * 256 + t;
        int c = y[b];
        const float* g  = gumbel + ((size_t)c * bs + b) * N_COMP;
        const float* lg = logits + c * N_COMP;
        float best = g[0] + lg[0];
        int bi = 0;
        #pragma unroll
        for (int k = 1; k < N_COMP; ++k) {
            float s = g[k] + lg[k];
            if (s > best) { best = s; bi = k; }  // strict > == first-max (jnp.argmax)
        }
        ck_arr[b] = (unsigned char)(c * N_COMP + bi);
        __threadfence();                      // device-scope visibility before sync
    }

    cg::this_grid().sync();                   // also orders LDS (implies barrier)

    // ---- phase 2a: scan ck_arr (8 KB = 512 uint4, 2/thread) -> LDS list ----
    {
        const uint4* ck4 = (const uint4*)ck_arr;
        #pragma unroll
        for (int p = 0; p < 2; ++p) {
            int idx = p * 256 + t;
            uint4 v = ck4[idx];
            int b0 = idx * 16;
            unsigned w[4] = {v.x, v.y, v.z, v.w};
            #pragma unroll
            for (int q = 0; q < 4; ++q) {
                #pragma unroll
                for (int e = 0; e < 4; ++e) {
                    if (((w[q] >> (8 * e)) & 0xFFu) == (unsigned)ck) {
                        int p2 = atomicAdd(&cnt, 1);
                        if (p2 < LIST_CAP) list[p2] = b0 + q * 4 + e;
                    }
                }
            }
        }
    }
    __syncthreads();

    const int n = min(cnt, LIST_CAP);   // ~82 typical

    const int wv   = t >> 6;        // wave 0..3
    const int lane = t & 63;
    const int mn   = lane & 15;     // A row / B col / D col index
    const int quad = lane >> 4;     // 0..3

    for (int s0 = 0; s0 < n; s0 += ZCAP) {
        const int ns = min(ZCAP, n - s0);

        // ---- phase 2b: stage + convert z rows (ns x 128 fp32, 12 f4/thread) ----
        #pragma unroll
        for (int p = 0; p < 12; ++p) {
            int f   = p * 256 + t;          // float4 index; row = f>>5, col4 = f&31
            int row = f >> 5;
            if (row < ns) {
                int samp = list[s0 + row];
                float4 v = *(const float4*)(z + (size_t)samp * N_Z + (f & 31) * 4);
                bf16x4 b4 = { (__bf16)v.x, (__bf16)v.y, (__bf16)v.z, (__bf16)v.w };
                *(bf16x4*)&zsb[row * 128 + (f & 31) * 4] = b4;
            }
        }
        __syncthreads();

        // ---- phase 2c: MFMA. wave wv handles N-tiles wv and wv+4 ----
        const int ntiles = (ns + 15) >> 4;
        #pragma unroll
        for (int half = 0; half < 2; ++half) {
            int nt = wv + half * 4;
            if (nt >= ntiles) break;          // wave-uniform
            int nb = nt * 16;
            int srow = nb + mn;               // sample row (>= ns: garbage ok)

            bf16x8 bf[4];
            #pragma unroll
            for (int ks = 0; ks < 4; ++ks)
                bf[ks] = *(const bf16x8*)&zsb[srow * 128 + ks * 32 + quad * 8];

            #pragma unroll
            for (int mt = 0; mt < 2; ++mt) {
                f32x4 acc = {0.f, 0.f, 0.f, 0.f};
                #pragma unroll
                for (int ks = 0; ks < 4; ++ks) {
                    bf16x8 af = *(const bf16x8*)&Lsb[(mt * 16 + mn) * 128 + ks * 32 + quad * 8];
                    acc = __builtin_amdgcn_mfma_f32_16x16x32_bf16(af, bf[ks], acc, 0, 0, 0);
                }
                // lane owns sample col mn, j rows quad*4+0..3
                int sidx = nb + mn;
                if (sidx < ns) {
                    int samp = list[s0 + sidx];
                    int j0 = jq * 32 + mt * 16 + quad * 4;
                    float4 mv = *(const float4*)(m + ck * N_Z + j0);
                    float4 o;
                    o.x = acc.x + mv.x;
                    o.y = acc.y + mv.y;
                    o.z = acc.z + mv.z;
                    o.w = acc.w + mv.w;
                    *(float4*)(out + (size_t)samp * N_Z + j0) = o;
                }
            }
        }
        __syncthreads();   // before next chunk overwrites zsb
    }
}

extern "C" void kernel_launch(void* const* d_in, const int* in_sizes, int n_in,
                              void* d_out, int out_size, void* d_ws, size_t ws_size,
                              hipStream_t stream)
{
    const float* z      = (const float*)d_in[0];
    const int*   y      = (const int*)d_in[1];
    const float* gumbel = (const float*)d_in[2];
    const float* m      = (const float*)d_in[3];
    const float* L      = (const float*)d_in[4];
    const float* logits = (const float*)d_in[5];
    float* out = (float*)d_out;

    int bs = in_sizes[0] / N_Z;  // 8192
    unsigned char* ck_arr = (unsigned char*)d_ws;   // bs bytes

    void* args[] = { (void*)&z, (void*)&y, (void*)&gumbel, (void*)&m,
                     (void*)&L, (void*)&logits, (void*)&out, (void*)&ck_arr,
                     (void*)&bs };
    hipLaunchCooperativeKernel((const void*)k_coop, dim3(N_CK, 4), dim3(256),
                               args, 0, stream);
}

// Round 13
// 80.641 us; speedup vs baseline: 1.7786x; 1.7786x over previous
//
#include <hip/hip_runtime.h>

// Forward collapse:
//   c = y[b]; k = argmax_k(logits[c,k] + gumbel[c,b,k]) (first max)
//   x[b,:] = L[c,k] @ z[b,:] + m[c,k,:]
//
// Round 13: R11 two-node structure, improved:
//  - Lsb pitch 136 bf16 (68 dw = 4 mod 32 banks) -> conflict-free b128 A-frag reads
//  - no zsb: B-fragments read z directly from global (L2-hot), cvt fp32->bf16 once/n-tile
//  - ck-scan + L loads prefetched into regs before the single staging barrier
//  - k_select at 256 thr/block

#define N_Z 128
#define N_COMP 10
#define N_CLASSES 10
#define N_CK (N_CLASSES * N_COMP)
#define LPITCH 136       // bf16 elements per Lsb row (272 B; 68 dw = 4 mod 32)
#define LIST_CAP 256

typedef __attribute__((ext_vector_type(4))) __bf16 bf16x4;
typedef __attribute__((ext_vector_type(8))) __bf16 bf16x8;
typedef __attribute__((ext_vector_type(4))) float f32x4;

// ---------------- K1: per-sample component select (atomic-free, fp32 exact) ----
__global__ __launch_bounds__(256) void k_select(
    const int* __restrict__ y, const float* __restrict__ gumbel,
    const float* __restrict__ logits, unsigned char* __restrict__ ck_arr, int bs)
{
    int b = blockIdx.x * 256 + threadIdx.x;
    if (b >= bs) return;
    int c = y[b];
    const float* g  = gumbel + ((size_t)c * bs + b) * N_COMP;   // 8-B aligned
    const float* lg = logits + c * N_COMP;
    float2 g01 = *(const float2*)(g + 0);
    float2 g23 = *(const float2*)(g + 2);
    float2 g45 = *(const float2*)(g + 4);
    float2 g67 = *(const float2*)(g + 6);
    float2 g89 = *(const float2*)(g + 8);
    float sc[N_COMP] = {
        g01.x + lg[0], g01.y + lg[1], g23.x + lg[2], g23.y + lg[3],
        g45.x + lg[4], g45.y + lg[5], g67.x + lg[6], g67.y + lg[7],
        g89.x + lg[8], g89.y + lg[9] };
    float best = sc[0];
    int bi = 0;
    #pragma unroll
    for (int k = 1; k < N_COMP; ++k)
        if (sc[k] > best) { best = sc[k]; bi = k; }  // strict > == first-max
    ck_arr[b] = (unsigned char)(c * N_COMP + bi);
}

// ---------------- K2: per-bucket MFMA GEMM (B direct from global) ----------------
__global__ __launch_bounds__(256) void k_mfma(
    const float* __restrict__ z, const float* __restrict__ m,
    const float* __restrict__ L, const unsigned char* __restrict__ ck_arr,
    float* __restrict__ out, int bs)
{
    const int ck = blockIdx.x;
    const int jh = blockIdx.y;   // j range [jh*64, jh*64+64)

    __shared__ __align__(16) __bf16 Lsb[64 * LPITCH];  // 17 KB, pitched rows
    __shared__ int list[LIST_CAP];                     // 1 KB
    __shared__ int cnt;

    const int t = threadIdx.x;
    if (t == 0) cnt = 0;

    // ---- prefetch: ck_arr scan words (2 uint4) + L half (8 float4) ----
    uint4 ckw[2];
    {
        const uint4* ck4 = (const uint4*)ck_arr;
        ckw[0] = ck4[t];
        ckw[1] = ck4[256 + t];
    }
    float4 lv[8];
    {
        const float4* Lg4 = (const float4*)(L + ((size_t)ck * N_Z + jh * 64) * N_Z);
        #pragma unroll
        for (int p = 0; p < 8; ++p) lv[p] = Lg4[p * 256 + t];
    }
    __syncthreads();   // cnt=0 visible

    // ---- scan: 32 samples/thread from the two prefetched uint4s ----
    #pragma unroll
    for (int h = 0; h < 2; ++h) {
        int b0 = (h * 256 + t) * 16;
        unsigned w[4] = {ckw[h].x, ckw[h].y, ckw[h].z, ckw[h].w};
        #pragma unroll
        for (int q = 0; q < 4; ++q) {
            #pragma unroll
            for (int e = 0; e < 4; ++e) {
                if (((w[q] >> (8 * e)) & 0xFFu) == (unsigned)ck) {
                    int p2 = atomicAdd(&cnt, 1);
                    if (p2 < LIST_CAP) list[p2] = b0 + q * 4 + e;
                }
            }
        }
    }
    // ---- store L half into pitched LDS (row = f>>5, col4 = f&31) ----
    #pragma unroll
    for (int p = 0; p < 8; ++p) {
        int f   = p * 256 + t;
        int row = f >> 5;
        int c4  = f & 31;
        bf16x4 b4 = { (__bf16)lv[p].x, (__bf16)lv[p].y, (__bf16)lv[p].z, (__bf16)lv[p].w };
        *(bf16x4*)&Lsb[row * LPITCH + c4 * 4] = b4;
    }
    __syncthreads();

    const int n = min(cnt, LIST_CAP);   // ~82 typical
    const int ntiles = (n + 15) >> 4;

    const int wv   = t >> 6;        // wave 0..3
    const int lane = t & 63;
    const int mn   = lane & 15;     // A row / B col / D col index
    const int quad = lane >> 4;     // 0..3

    for (int nt = wv; nt < ntiles; nt += 4) {
        const int nb = nt * 16;
        const int sidx = nb + mn;
        const int samp = list[sidx < n ? sidx : n - 1];   // clamp: dup row, result masked
        const float* zrow = z + (size_t)samp * N_Z;

        // ---- B-fragments direct from global: 8 f32 per ks, cvt to bf16 ----
        bf16x8 bf[4];
        #pragma unroll
        for (int ks = 0; ks < 4; ++ks) {
            float4 z0 = *(const float4*)(zrow + ks * 32 + quad * 8);
            float4 z1 = *(const float4*)(zrow + ks * 32 + quad * 8 + 4);
            bf16x8 b8 = { (__bf16)z0.x, (__bf16)z0.y, (__bf16)z0.z, (__bf16)z0.w,
                          (__bf16)z1.x, (__bf16)z1.y, (__bf16)z1.z, (__bf16)z1.w };
            bf[ks] = b8;
        }

        #pragma unroll
        for (int mt = 0; mt < 4; ++mt) {
            f32x4 acc = {0.f, 0.f, 0.f, 0.f};
            #pragma unroll
            for (int ks = 0; ks < 4; ++ks) {
                bf16x8 af = *(const bf16x8*)&Lsb[(mt * 16 + mn) * LPITCH + ks * 32 + quad * 8];
                acc = __builtin_amdgcn_mfma_f32_16x16x32_bf16(af, bf[ks], acc, 0, 0, 0);
            }
            // lane owns sample col mn, j rows quad*4+0..3
            if (sidx < n) {
                int j0 = jh * 64 + mt * 16 + quad * 4;
                float4 mv = *(const float4*)(m + ck * N_Z + j0);
                float4 o;
                o.x = acc.x + mv.x;
                o.y = acc.y + mv.y;
                o.z = acc.z + mv.z;
                o.w = acc.w + mv.w;
                *(float4*)(out + (size_t)list[sidx] * N_Z + j0) = o;
            }
        }
    }
}

extern "C" void kernel_launch(void* const* d_in, const int* in_sizes, int n_in,
                              void* d_out, int out_size, void* d_ws, size_t ws_size,
                              hipStream_t stream)
{
    const float* z      = (const float*)d_in[0];
    const int*   y      = (const int*)d_in[1];
    const float* gumbel = (const float*)d_in[2];
    const float* m      = (const float*)d_in[3];
    const float* L      = (const float*)d_in[4];
    const float* logits = (const float*)d_in[5];
    float* out = (float*)d_out;

    const int bs = in_sizes[0] / N_Z;  // 8192

    unsigned char* ck_arr = (unsigned char*)d_ws;   // bs bytes

    k_select<<<(bs + 255) / 256, 256, 0, stream>>>(y, gumbel, logits, ck_arr, bs);
    k_mfma<<<dim3(N_CK, 2), 256, 0, stream>>>(z, m, L, ck_arr, out, bs);
}